// Round 8
// baseline (150.711 us; speedup 1.0000x reference)
//
#include <hip/hip_runtime.h>
#include <cmath>

// CriticSNN forward: BATCH=65536, STATE_DIM=6, HIDDEN=128, NUM_STEPS=8, OUT=1
// One wave per batch element-QUAD; lane l owns neurons l and l+64 of each.
// Spikes are binary -> ballots; matmuls are masked column sums from LDS.
//
// v7: v4 structure (all-LDS f32x4 table, proven best at 52us) + 4-element
// interleave per wave. Evidence: v4 is stall-bound at 58% VALUBusy with only
// 4 waves/SIMD (LDS-capped); VGPR use was 56 of the 128 cap. Four
// independent step-chains per wave fill each other's LDS-latency holes and
// quadruple loads in flight. v6b taught us eviction trades latency for
// parallelism at a loss -- so the table stays fully in LDS.

typedef float f32x2 __attribute__((ext_vector_type(2)));
typedef float f32x4 __attribute__((ext_vector_type(4)));

constexpr int BATCH = 65536;
constexpr int HID   = 128;
constexpr int SDIM  = 6;
constexpr int NSTEP = 8;
constexpr int BLOCK = 1024;                         // 16 waves/block
constexpr int GRID  = 256;                          // 1 block per CU
constexpr int WAVES_TOTAL = GRID * (BLOCK / 64);    // 4096
constexpr int ELEMS_PER_WAVE = BATCH / WAVES_TOTAL; // 16
constexpr int NE = 4;                               // elements interleaved
constexpr int NQUAD = ELEMS_PER_WAVE / NE;          // 4 outer iterations

__global__ __launch_bounds__(BLOCK) void snn_fwd(
    const float* __restrict__ state,
    const float* __restrict__ w_fc1,
    const float* __restrict__ w_rec1,
    const float* __restrict__ w_fc2,
    const float* __restrict__ w_rec2,
    const float* __restrict__ w_mean,
    const float* __restrict__ w_std,
    const float* __restrict__ p_alpha1, const float* __restrict__ p_beta1,
    const float* __restrict__ p_thr1,
    const float* __restrict__ p_alpha2, const float* __restrict__ p_beta2,
    const float* __restrict__ p_thr2,
    float* __restrict__ out)
{
    // entry (j, l) at index j*64 + (l ^ (j & 63)); XOR swizzle keeps both the
    // staging writes and the uniform-j gather reads conflict-free.
    __shared__ f32x4 ldw[HID * 64];   // 128 KiB

    const int tid = threadIdx.x;

    for (int v = tid; v < HID * 64; v += BLOCK) {
        const int l = v >> 7;        // 0..63
        const int j = v & 127;       // consecutive lanes -> consecutive j
        const int pos = (j << 6) | (l ^ (j & 63));
        f32x4 w;
        w.x = w_rec1[l * HID + j];
        w.y = w_rec1[(l + 64) * HID + j];
        w.z = w_fc2 [l * HID + j];
        w.w = w_fc2 [(l + 64) * HID + j];
        ldw[pos] = w;
    }

    const int lane  = tid & 63;
    const int gwave = blockIdx.x * (BLOCK / 64) + (tid >> 6);

    // small weights -> registers
    f32x2 w1[SDIM];
    #pragma unroll
    for (int k = 0; k < SDIM; ++k) {
        w1[k].x = w_fc1[lane * SDIM + k];
        w1[k].y = w_fc1[(lane + 64) * SDIM + k];
    }
    const float wm_a = w_mean[lane], wm_b = w_mean[lane + 64];
    const float ws_a = w_std [lane], ws_b = w_std [lane + 64];

    const float a1 = fminf(fmaxf(p_alpha1[0], 0.f), 1.f);
    const float b1 = fminf(fmaxf(p_beta1 [0], 0.f), 1.f);
    const float a2 = fminf(fmaxf(p_alpha2[0], 0.f), 1.f);
    const float b2 = fminf(fmaxf(p_beta2 [0], 0.f), 1.f);
    const float t1 = p_thr1[0];
    const float t2 = p_thr2[0];
    const f32x2 a1v = {a1, a1}, b1v = {b1, b1}, a2v = {a2, a2}, b2v = {b2, b2};

    const float* __restrict__ rec2_a = w_rec2 + lane * HID;
    const float* __restrict__ rec2_b = w_rec2 + (lane + 64) * HID;

    __syncthreads();

    // fused gather over one spike mask: rec1 (next step) into r, fc2 (this
    // step) into f. One ds_read_b128 per set bit; hand-rotated.
    auto walk2 = [&](unsigned long long m, const f32x4* __restrict__ base,
                     f32x2& f, f32x2& r) {
        if (!m) return;
        int j = __builtin_ctzll(m); m &= m - 1;
        f32x4 w = base[(j << 6) | (lane ^ j)];
        while (m) {
            const int j2 = __builtin_ctzll(m); m &= m - 1;
            const f32x4 w2 = base[(j2 << 6) | (lane ^ j2)];
            r += __builtin_shufflevector(w, w, 0, 1);
            f += __builtin_shufflevector(w, w, 2, 3);
            w = w2;
        }
        r += __builtin_shufflevector(w, w, 0, 1);
        f += __builtin_shufflevector(w, w, 2, 3);
    };
    auto walkg = [&](unsigned long long m, int jbase, f32x2& f) {
        while (m) {
            const int j = __builtin_ctzll(m) + jbase; m &= m - 1;
            f.x += rec2_a[j];
            f.y += rec2_b[j];
        }
    };

    const f32x4* __restrict__ baseLo = ldw;
    const f32x4* __restrict__ baseHi = ldw + (64 << 6);

    for (int q = 0; q < NQUAD; ++q) {
        int bb[NE];
        #pragma unroll
        for (int i = 0; i < NE; ++i) bb[i] = gwave + WAVES_TOTAL * (q * NE + i);

        // cur1_in = state @ w_fc1.T (constant across steps)
        f32x2 cur[NE];
        #pragma unroll
        for (int i = 0; i < NE; ++i) {
            f32x2 c = {0.f, 0.f};
            #pragma unroll
            for (int k = 0; k < SDIM; ++k) {
                const float s = state[bb[i] * SDIM + k];   // wave-broadcast
                const f32x2 sv = {s, s};
                c = __builtin_elementwise_fma(sv, w1[k], c);
            }
            cur[i] = c;
        }

        f32x2 s1[NE], m1[NE], s2[NE], m2[NE], r[NE], cnt[NE];
        bool k1a[NE], k1b[NE], k2a[NE], k2b[NE];
        unsigned long long M2a[NE], M2b[NE];
        #pragma unroll
        for (int i = 0; i < NE; ++i) {
            s1[i] = (f32x2){0.f, 0.f}; m1[i] = (f32x2){0.f, 0.f};
            s2[i] = (f32x2){0.f, 0.f}; m2[i] = (f32x2){0.f, 0.f};
            r [i] = (f32x2){0.f, 0.f}; cnt[i] = (f32x2){0.f, 0.f};
            k1a[i] = k1b[i] = k2a[i] = k2b[i] = false;
            M2a[i] = 0ull; M2b[i] = 0ull;
        }

        #pragma unroll 1
        for (int t = 0; t < NSTEP; ++t) {
            // ----- layer 1 (all elements) -----
            unsigned long long M1a[NE], M1b[NE];
            #pragma unroll
            for (int i = 0; i < NE; ++i) {
                s1[i] = __builtin_elementwise_fma(a1v, s1[i], cur[i] + r[i]);
                const f32x2 rst1 = {k1a[i] ? t1 : 0.f, k1b[i] ? t1 : 0.f};
                m1[i] = __builtin_elementwise_fma(b1v, m1[i], s1[i]) - rst1;
                k1a[i] = (m1[i].x - t1) > 0.f;
                k1b[i] = (m1[i].y - t1) > 0.f;
                M1a[i] = __ballot(k1a[i]);
                M1b[i] = __ballot(k1b[i]);
            }

            // ----- fused gathers: fc2 (this step) + rec1 (next step) -----
            // 8 independent walks -> loads from different elements overlap.
            f32x2 f[NE];
            #pragma unroll
            for (int i = 0; i < NE; ++i) {
                f[i] = (f32x2){0.f, 0.f};
                r[i] = (f32x2){0.f, 0.f};
            }
            #pragma unroll
            for (int i = 0; i < NE; ++i) walk2(M1a[i], baseLo, f[i], r[i]);
            #pragma unroll
            for (int i = 0; i < NE; ++i) walk2(M1b[i], baseHi, f[i], r[i]);

            // rare layer-2 recurrence
            unsigned long long anyM2 = 0ull;
            #pragma unroll
            for (int i = 0; i < NE; ++i) anyM2 |= M2a[i] | M2b[i];
            if (anyM2 != 0ull) {
                #pragma unroll
                for (int i = 0; i < NE; ++i) {
                    walkg(M2a[i], 0,  f[i]);
                    walkg(M2b[i], 64, f[i]);
                }
            }

            // ----- layer 2 (all elements) -----
            #pragma unroll
            for (int i = 0; i < NE; ++i) {
                s2[i] = __builtin_elementwise_fma(a2v, s2[i], f[i]);
                const f32x2 rst2 = {k2a[i] ? t2 : 0.f, k2b[i] ? t2 : 0.f};
                m2[i] = __builtin_elementwise_fma(b2v, m2[i], s2[i]) - rst2;
                k2a[i] = (m2[i].x - t2) > 0.f;
                k2b[i] = (m2[i].y - t2) > 0.f;
                M2a[i] = __ballot(k2a[i]);
                M2b[i] = __ballot(k2b[i]);
                const f32x2 one = {k2a[i] ? 1.f : 0.f, k2b[i] ? 1.f : 0.f};
                cnt[i] += one;
            }
        }

        // ----- head: dot(avg_spikes, w_mean/w_std) + activations -----
        #pragma unroll
        for (int i = 0; i < NE; ++i) {
            const float av_a = cnt[i].x * (1.f / (float)NSTEP);
            const float av_b = cnt[i].y * (1.f / (float)NSTEP);
            float dm = av_a * wm_a + av_b * wm_b;
            float ds = av_a * ws_a + av_b * ws_b;
            #pragma unroll
            for (int off = 32; off > 0; off >>= 1) {
                dm += __shfl_xor(dm, off, 64);
                ds += __shfl_xor(ds, off, 64);
            }
            if (lane == 0) {
                out[bb[i]] = tanhf(dm);
                const float sg = 1.f / (1.f + expf(-(ds + 2.f)));
                out[BATCH + bb[i]] = 1.9f * sg + 0.1f;
            }
        }
    }
}

extern "C" void kernel_launch(void* const* d_in, const int* in_sizes, int n_in,
                              void* d_out, int out_size, void* d_ws, size_t ws_size,
                              hipStream_t stream) {
    (void)in_sizes; (void)n_in; (void)d_ws; (void)ws_size; (void)out_size;
    snn_fwd<<<GRID, BLOCK, 0, stream>>>(
        (const float*)d_in[0],  // state
        (const float*)d_in[1],  // w_fc1
        (const float*)d_in[2],  // w_rec1
        (const float*)d_in[3],  // w_fc2
        (const float*)d_in[4],  // w_rec2
        (const float*)d_in[5],  // w_mean
        (const float*)d_in[6],  // w_std
        (const float*)d_in[7],  // alpha1
        (const float*)d_in[8],  // beta1
        (const float*)d_in[9],  // thr1
        (const float*)d_in[10], // alpha2
        (const float*)d_in[11], // beta2
        (const float*)d_in[12], // thr2
        (float*)d_out);
}